// Round 1
// baseline (2777.726 us; speedup 1.0000x reference)
//
#include <hip/hip_runtime.h>
#include <hip/hip_bf16.h>
#include <math.h>

// Sizes (fixed by the problem)
#define T_STEPS 1024
#define B_SZ 32
#define F_SZ 2048
#define H_SZ 64
#define G4 256      // 4*H
#define C_SZ 101

// ---------------------------------------------------------------------------
// Phase 1: x_proj[t,b,j] = sum_f x[t,b,f] * W_ih[j,f] + b_ih[j] + b_hh[j]
// Grid: T_STEPS blocks, 256 threads. Each block handles one t-slice (32 rows),
// each thread one gate column j (computes all 32 batch outputs).
// x staged in LDS (read once from HBM); W_ih row streamed per-thread (L2-hot).
// ---------------------------------------------------------------------------
__global__ __launch_bounds__(256) void xproj_kernel(
    const float* __restrict__ x, const float* __restrict__ W_ih,
    const float* __restrict__ b_ih, const float* __restrict__ b_hh,
    float* __restrict__ xproj) {
  const int t = blockIdx.x;
  const int j = threadIdx.x;  // 0..255

  __shared__ float Alds[B_SZ][64];  // 32x64 chunk of x

  float acc[B_SZ];
#pragma unroll
  for (int b = 0; b < B_SZ; ++b) acc[b] = 0.f;

  const float* xrow = x + (size_t)t * B_SZ * F_SZ;
  const int r = threadIdx.x >> 3;          // 0..31 row
  const int cbase = (threadIdx.x & 7) * 8; // 0..56

  for (int k0 = 0; k0 < F_SZ; k0 += 64) {
    // stage 32x64 x-chunk: each thread loads 8 floats (2 x float4)
    const float4* src = (const float4*)(xrow + (size_t)r * F_SZ + k0 + cbase);
    float4 v0 = src[0];
    float4 v1 = src[1];
    *(float4*)&Alds[r][cbase] = v0;
    *(float4*)&Alds[r][cbase + 4] = v1;
    __syncthreads();

    // W_ih row-j chunk into registers (16 x float4 = 64 floats)
    float4 w4[16];
    const float4* wsrc = (const float4*)(W_ih + (size_t)j * F_SZ + k0);
#pragma unroll
    for (int i = 0; i < 16; ++i) w4[i] = wsrc[i];

#pragma unroll
    for (int k4 = 0; k4 < 16; ++k4) {
      const float4 wv = w4[k4];
#pragma unroll
      for (int b = 0; b < B_SZ; ++b) {
        const float4 a = *(const float4*)&Alds[b][k4 * 4];
        acc[b] += a.x * wv.x + a.y * wv.y + a.z * wv.z + a.w * wv.w;
      }
    }
    __syncthreads();
  }

  const float bias = b_ih[j] + b_hh[j];
#pragma unroll
  for (int b = 0; b < B_SZ; ++b) {
    xproj[((size_t)t * B_SZ + b) * G4 + j] = acc[b] + bias;
  }
}

// ---------------------------------------------------------------------------
// Phase 2: sequential LSTM scan. 32 blocks (one per batch element, chains are
// independent), 256 threads (one per gate column j). Persistent over t.
// W_hh row j in registers; h, c in LDS; gate activations via LDS exchange.
// ---------------------------------------------------------------------------
__global__ __launch_bounds__(256) void lstm_scan_kernel(
    const float* __restrict__ xproj, const float* __restrict__ W_hh,
    float* __restrict__ hT) {
  const int b = blockIdx.x;   // 0..31
  const int j = threadIdx.x;  // 0..255

  __shared__ float h_lds[H_SZ];
  __shared__ float c_lds[H_SZ];
  __shared__ float act[G4];

  // W_hh[j][0..63] into registers
  float w[H_SZ];
  {
    const float4* wsrc = (const float4*)(W_hh + (size_t)j * H_SZ);
#pragma unroll
    for (int i = 0; i < 16; ++i) {
      float4 v = wsrc[i];
      w[4 * i + 0] = v.x;
      w[4 * i + 1] = v.y;
      w[4 * i + 2] = v.z;
      w[4 * i + 3] = v.w;
    }
  }

  if (j < H_SZ) {
    h_lds[j] = 0.f;
    c_lds[j] = 0.f;
  }
  __syncthreads();

  const float* xp = xproj + (size_t)b * G4 + j;  // stride per t: B*G4
  float xv = xp[0];

  for (int t = 0; t < T_STEPS; ++t) {
    // prefetch next step's x_proj early to hide latency
    float xn = (t < T_STEPS - 1) ? xp[(size_t)(t + 1) * B_SZ * G4] : 0.f;

    float pre = xv;
#pragma unroll
    for (int k4 = 0; k4 < 16; ++k4) {
      const float4 h4 = *(const float4*)&h_lds[k4 * 4];
      pre += h4.x * w[4 * k4 + 0] + h4.y * w[4 * k4 + 1] +
             h4.z * w[4 * k4 + 2] + h4.w * w[4 * k4 + 3];
    }

    // gate order: i [0,64), f [64,128), g [128,192), o [192,256)
    float a;
    if (j < 128 || j >= 192) {
      a = 1.f / (1.f + expf(-pre));  // sigmoid (i, f, o)
    } else {
      a = tanhf(pre);  // g
    }
    act[j] = a;
    __syncthreads();

    if (j < H_SZ) {
      const float c_new = act[64 + j] * c_lds[j] + act[j] * act[128 + j];
      const float h_new = act[192 + j] * tanhf(c_new);
      c_lds[j] = c_new;
      h_lds[j] = h_new;
    }
    __syncthreads();

    xv = xn;
  }

  if (j < H_SZ) hT[b * H_SZ + j] = h_lds[j];
}

// ---------------------------------------------------------------------------
// Phase 3: out[b][c] = sum_k hT[b][k] * W_lin[c][k] + b_lin[c]
// ---------------------------------------------------------------------------
__global__ __launch_bounds__(128) void final_linear_kernel(
    const float* __restrict__ hT, const float* __restrict__ W_lin,
    const float* __restrict__ b_lin, float* __restrict__ out) {
  const int b = blockIdx.x;
  const int cc = threadIdx.x;

  __shared__ float h_l[H_SZ];
  if (threadIdx.x < H_SZ) h_l[threadIdx.x] = hT[b * H_SZ + threadIdx.x];
  __syncthreads();

  if (cc < C_SZ) {
    float acc = b_lin[cc];
    const float* wr = W_lin + (size_t)cc * H_SZ;
#pragma unroll
    for (int k = 0; k < H_SZ; ++k) acc += h_l[k] * wr[k];
    out[b * C_SZ + cc] = acc;
  }
}

// ---------------------------------------------------------------------------
extern "C" void kernel_launch(void* const* d_in, const int* in_sizes, int n_in,
                              void* d_out, int out_size, void* d_ws,
                              size_t ws_size, hipStream_t stream) {
  const float* x = (const float*)d_in[0];      // [T,B,F]
  const float* W_ih = (const float*)d_in[1];   // [4H,F]
  const float* W_hh = (const float*)d_in[2];   // [4H,H]
  const float* b_ih = (const float*)d_in[3];   // [4H]
  const float* b_hh = (const float*)d_in[4];   // [4H]
  const float* W_lin = (const float*)d_in[5];  // [C,H]
  const float* b_lin = (const float*)d_in[6];  // [C]
  float* out = (float*)d_out;                  // [B,C]

  // workspace layout: x_proj (T*B*4H fp32 = 32 MB), then hT (B*H fp32)
  float* xproj = (float*)d_ws;
  float* hT = (float*)((char*)d_ws + (size_t)T_STEPS * B_SZ * G4 * sizeof(float));

  xproj_kernel<<<T_STEPS, 256, 0, stream>>>(x, W_ih, b_ih, b_hh, xproj);
  lstm_scan_kernel<<<B_SZ, 256, 0, stream>>>(xproj, W_hh, hT);
  final_linear_kernel<<<B_SZ, 128, 0, stream>>>(hT, W_lin, b_lin, out);
}

// Round 2
// 792.261 us; speedup vs baseline: 3.5061x; 3.5061x over previous
//
#include <hip/hip_runtime.h>
#include <hip/hip_bf16.h>
#include <math.h>

// Sizes (fixed by the problem)
#define T_STEPS 1024
#define B_SZ 32
#define F_SZ 2048
#define H_SZ 64
#define G4 256      // 4*H
#define C_SZ 101

typedef __bf16 bf16x8 __attribute__((ext_vector_type(8)));
typedef unsigned short u16x8 __attribute__((ext_vector_type(8)));
typedef float f32x4 __attribute__((ext_vector_type(4)));

// Round-to-nearest-even fp32 -> bf16 split: f ~= hi + lo (each bf16).
__device__ __forceinline__ void split_bf16(float f, unsigned short& h,
                                           unsigned short& l) {
  unsigned u = __builtin_bit_cast(unsigned, f);
  unsigned rh = (u + 0x7FFFu + ((u >> 16) & 1u)) >> 16;
  h = (unsigned short)rh;
  float d = f - __builtin_bit_cast(float, rh << 16);
  unsigned ud = __builtin_bit_cast(unsigned, d);
  l = (unsigned short)((ud + 0x7FFFu + ((ud >> 16) & 1u)) >> 16);
}

// ---------------------------------------------------------------------------
// Phase 1 (MFMA): xproj[t,b,j] = sum_f x[t,b,f]*W_ih[j,f] + b_ih[j] + b_hh[j]
// C[M=32768, N=256] = X[M,K=2048] * W^T.  bf16-split: hi*hi + hi*lo + lo*hi.
// 256 blocks, each computes a 128x256 tile. 8 waves (2M x 4N), each wave a
// 64x64 sub-tile = 4x4 fragments of mfma_f32_16x16x32_bf16.  BK=32.
// fp32->bf16 hi/lo conversion fused into LDS staging; next K-tile register-
// prefetched between the barriers so global latency hides under MFMA.
// ---------------------------------------------------------------------------
#define BM 128
#define BK 32
#define LDSP 40  // padded row stride in ushorts (32 + 8): breaks bank conflicts

__global__ __launch_bounds__(512) void xproj_mfma(
    const float* __restrict__ x, const float* __restrict__ W_ih,
    const float* __restrict__ b_ih, const float* __restrict__ b_hh,
    float* __restrict__ xproj) {
  __shared__ alignas(16) unsigned short Xhi[BM][LDSP];
  __shared__ alignas(16) unsigned short Xlo[BM][LDSP];
  __shared__ alignas(16) unsigned short Whi[G4][LDSP];
  __shared__ alignas(16) unsigned short Wlo[G4][LDSP];

  const int tid = threadIdx.x;
  const int lane = tid & 63;
  const int wave = tid >> 6;  // 0..7
  const int wm = wave >> 2;   // 0..1 (M)
  const int wn = wave & 3;    // 0..3 (N)
  const size_t R0 = (size_t)blockIdx.x * BM;

  // staging assignment: X: 128 rows x 32k, 4 threads/row (8 floats each)
  const int xr = tid >> 2;
  const int xs = (tid & 3) * 8;
  // W: 256 rows x 32k, 2 threads/row (16 floats each)
  const int wr = tid >> 1;
  const int wsg = (tid & 1) * 16;

  const float* xbase = x + (R0 + xr) * (size_t)F_SZ + xs;
  const float* wbase = W_ih + (size_t)wr * F_SZ + wsg;

  // prologue: prefetch tile kt=0 into registers
  float4 xa = *(const float4*)(xbase + 0);
  float4 xb = *(const float4*)(xbase + 4);
  float4 wa = *(const float4*)(wbase + 0);
  float4 wb = *(const float4*)(wbase + 4);
  float4 wc = *(const float4*)(wbase + 8);
  float4 wd = *(const float4*)(wbase + 12);

  f32x4 acc[4][4] = {};

  const int ar = lane & 15;         // fragment row (A) / col (B)
  const int ak = (lane >> 4) * 8;   // k-offset within BK

  for (int kt = 0; kt < F_SZ; kt += BK) {
    // ---- convert current prefetch regs -> LDS (hi/lo bf16) ----
    {
      float xf[8] = {xa.x, xa.y, xa.z, xa.w, xb.x, xb.y, xb.z, xb.w};
      u16x8 xh, xl;
#pragma unroll
      for (int i = 0; i < 8; ++i) {
        unsigned short h, l;
        split_bf16(xf[i], h, l);
        xh[i] = h;
        xl[i] = l;
      }
      *(u16x8*)&Xhi[xr][xs] = xh;
      *(u16x8*)&Xlo[xr][xs] = xl;

      float wf[16] = {wa.x, wa.y, wa.z, wa.w, wb.x, wb.y, wb.z, wb.w,
                      wc.x, wc.y, wc.z, wc.w, wd.x, wd.y, wd.z, wd.w};
      u16x8 wh0, wl0, wh1, wl1;
#pragma unroll
      for (int i = 0; i < 8; ++i) {
        unsigned short h, l;
        split_bf16(wf[i], h, l);
        wh0[i] = h;
        wl0[i] = l;
        split_bf16(wf[8 + i], h, l);
        wh1[i] = h;
        wl1[i] = l;
      }
      *(u16x8*)&Whi[wr][wsg] = wh0;
      *(u16x8*)&Whi[wr][wsg + 8] = wh1;
      *(u16x8*)&Wlo[wr][wsg] = wl0;
      *(u16x8*)&Wlo[wr][wsg + 8] = wl1;
    }
    __syncthreads();

    // ---- prefetch next K-tile (in flight during MFMA) ----
    const int ktn = (kt + BK < F_SZ) ? kt + BK : kt;
    xa = *(const float4*)(xbase + ktn + 0);
    xb = *(const float4*)(xbase + ktn + 4);
    wa = *(const float4*)(wbase + ktn + 0);
    wb = *(const float4*)(wbase + ktn + 4);
    wc = *(const float4*)(wbase + ktn + 8);
    wd = *(const float4*)(wbase + ktn + 12);

    // ---- fragments + MFMA ----
    bf16x8 Ah[4], Al[4], Bh[4], Bl[4];
#pragma unroll
    for (int fm = 0; fm < 4; ++fm) {
      const int row = wm * 64 + fm * 16 + ar;
      Ah[fm] = __builtin_bit_cast(bf16x8, *(const u16x8*)&Xhi[row][ak]);
      Al[fm] = __builtin_bit_cast(bf16x8, *(const u16x8*)&Xlo[row][ak]);
    }
#pragma unroll
    for (int fn = 0; fn < 4; ++fn) {
      const int col = wn * 64 + fn * 16 + ar;
      Bh[fn] = __builtin_bit_cast(bf16x8, *(const u16x8*)&Whi[col][ak]);
      Bl[fn] = __builtin_bit_cast(bf16x8, *(const u16x8*)&Wlo[col][ak]);
    }
#pragma unroll
    for (int fm = 0; fm < 4; ++fm) {
#pragma unroll
      for (int fn = 0; fn < 4; ++fn) {
        acc[fm][fn] = __builtin_amdgcn_mfma_f32_16x16x32_bf16(
            Ah[fm], Bh[fn], acc[fm][fn], 0, 0, 0);
        acc[fm][fn] = __builtin_amdgcn_mfma_f32_16x16x32_bf16(
            Ah[fm], Bl[fn], acc[fm][fn], 0, 0, 0);
        acc[fm][fn] = __builtin_amdgcn_mfma_f32_16x16x32_bf16(
            Al[fm], Bh[fn], acc[fm][fn], 0, 0, 0);
      }
    }
    __syncthreads();
  }

  // ---- epilogue: C/D layout col=lane&15, row=(lane>>4)*4+reg ----
  const int cr = (lane >> 4) * 4;
  const int cc = lane & 15;
#pragma unroll
  for (int fn = 0; fn < 4; ++fn) {
    const int gj = wn * 64 + fn * 16 + cc;
    const float bias = b_ih[gj] + b_hh[gj];
#pragma unroll
    for (int fm = 0; fm < 4; ++fm) {
      const size_t gr = R0 + wm * 64 + fm * 16 + cr;
#pragma unroll
      for (int r = 0; r < 4; ++r) {
        xproj[(gr + r) * G4 + gj] = acc[fm][fn][r] + bias;
      }
    }
  }
}

// ---------------------------------------------------------------------------
// Phase 2: sequential LSTM scan. 32 blocks (one per batch element), 256
// threads (one per gate column j). Dot h.W_hh with 4 split accumulators
// (short dep chain); c/h update done redundantly by all threads (c kept in
// registers, 4 replicas). 2 barriers per step.
// ---------------------------------------------------------------------------
__global__ __launch_bounds__(256) void lstm_scan_kernel(
    const float* __restrict__ xproj, const float* __restrict__ W_hh,
    float* __restrict__ hT) {
  const int b = blockIdx.x;   // 0..31
  const int j = threadIdx.x;  // 0..255
  const int u = j & 63;       // hidden index this thread helps update

  __shared__ float h_lds[H_SZ];
  __shared__ float act[G4];

  float w[H_SZ];
  {
    const float4* wsrc = (const float4*)(W_hh + (size_t)j * H_SZ);
#pragma unroll
    for (int i = 0; i < 16; ++i) {
      float4 v = wsrc[i];
      w[4 * i + 0] = v.x;
      w[4 * i + 1] = v.y;
      w[4 * i + 2] = v.z;
      w[4 * i + 3] = v.w;
    }
  }

  float c_reg = 0.f;  // private replica of c[u]
  if (j < H_SZ) h_lds[j] = 0.f;
  __syncthreads();

  const float* xp = xproj + (size_t)b * G4 + j;  // stride per t: B*G4
  float xv = xp[0];

  for (int t = 0; t < T_STEPS; ++t) {
    float xn = (t < T_STEPS - 1) ? xp[(size_t)(t + 1) * B_SZ * G4] : 0.f;

    // dot(h, W_hh[j]) with 4 independent partial sums
    float p0 = xv, p1 = 0.f, p2 = 0.f, p3 = 0.f;
#pragma unroll
    for (int k = 0; k < 4; ++k) {
      const float4 h0 = *(const float4*)&h_lds[(4 * k + 0) * 4];
      const float4 h1 = *(const float4*)&h_lds[(4 * k + 1) * 4];
      const float4 h2 = *(const float4*)&h_lds[(4 * k + 2) * 4];
      const float4 h3 = *(const float4*)&h_lds[(4 * k + 3) * 4];
      const int kb = 16 * k;
      p0 += h0.x * w[kb + 0] + h0.y * w[kb + 1] + h0.z * w[kb + 2] + h0.w * w[kb + 3];
      p1 += h1.x * w[kb + 4] + h1.y * w[kb + 5] + h1.z * w[kb + 6] + h1.w * w[kb + 7];
      p2 += h2.x * w[kb + 8] + h2.y * w[kb + 9] + h2.z * w[kb + 10] + h2.w * w[kb + 11];
      p3 += h3.x * w[kb + 12] + h3.y * w[kb + 13] + h3.z * w[kb + 14] + h3.w * w[kb + 15];
    }
    const float pre = (p0 + p1) + (p2 + p3);

    // gate order: i [0,64), f [64,128), g [128,192), o [192,256)
    float a;
    if (j < 128 || j >= 192) {
      a = 1.f / (1.f + expf(-pre));  // sigmoid (i, f, o): wave-uniform branch
    } else {
      a = tanhf(pre);  // g
    }
    act[j] = a;
    __syncthreads();

    // redundant update across all 256 threads (4 replicas per hidden unit)
    const float ai = act[u];
    const float af = act[64 + u];
    const float ag = act[128 + u];
    const float ao = act[192 + u];
    c_reg = af * c_reg + ai * ag;
    const float hn = ao * tanhf(c_reg);
    h_lds[u] = hn;  // 4 threads write the same value: benign
    __syncthreads();

    xv = xn;
  }

  if (j < H_SZ) hT[b * H_SZ + j] = h_lds[j];
}

// ---------------------------------------------------------------------------
// Phase 3: out[b][c] = sum_k hT[b][k] * W_lin[c][k] + b_lin[c]
// ---------------------------------------------------------------------------
__global__ __launch_bounds__(128) void final_linear_kernel(
    const float* __restrict__ hT, const float* __restrict__ W_lin,
    const float* __restrict__ b_lin, float* __restrict__ out) {
  const int b = blockIdx.x;
  const int cc = threadIdx.x;

  __shared__ float h_l[H_SZ];
  if (threadIdx.x < H_SZ) h_l[threadIdx.x] = hT[b * H_SZ + threadIdx.x];
  __syncthreads();

  if (cc < C_SZ) {
    float acc = b_lin[cc];
    const float* wr = W_lin + (size_t)cc * H_SZ;
#pragma unroll
    for (int k = 0; k < H_SZ; ++k) acc += h_l[k] * wr[k];
    out[b * C_SZ + cc] = acc;
  }
}

// ---------------------------------------------------------------------------
extern "C" void kernel_launch(void* const* d_in, const int* in_sizes, int n_in,
                              void* d_out, int out_size, void* d_ws,
                              size_t ws_size, hipStream_t stream) {
  const float* x = (const float*)d_in[0];      // [T,B,F]
  const float* W_ih = (const float*)d_in[1];   // [4H,F]
  const float* W_hh = (const float*)d_in[2];   // [4H,H]
  const float* b_ih = (const float*)d_in[3];   // [4H]
  const float* b_hh = (const float*)d_in[4];   // [4H]
  const float* W_lin = (const float*)d_in[5];  // [C,H]
  const float* b_lin = (const float*)d_in[6];  // [C]
  float* out = (float*)d_out;                  // [B,C]

  // workspace layout: x_proj (T*B*4H fp32 = 32 MB), then hT (B*H fp32)
  float* xproj = (float*)d_ws;
  float* hT = (float*)((char*)d_ws + (size_t)T_STEPS * B_SZ * G4 * sizeof(float));

  xproj_mfma<<<(T_STEPS * B_SZ) / BM, 512, 0, stream>>>(x, W_ih, b_ih, b_hh,
                                                        xproj);
  lstm_scan_kernel<<<B_SZ, 256, 0, stream>>>(xproj, W_hh, hT);
  final_linear_kernel<<<B_SZ, 128, 0, stream>>>(hT, W_lin, b_lin, out);
}